// Round 1
// baseline (418.093 us; speedup 1.0000x reference)
//
#include <hip/hip_runtime.h>

typedef unsigned short u16;
typedef unsigned int u32;

#define FULL 12288
#define NE 1024
#define ITERSZ 4096
#define NB 8
#define TT 1024
#define MROWS 8192

typedef __bf16 bf16x8 __attribute__((ext_vector_type(8)));
typedef float f32x4 __attribute__((ext_vector_type(4)));
typedef const __attribute__((address_space(1))) void GVoid;
typedef __attribute__((address_space(3))) void LVoid;

__device__ __forceinline__ u16 f2b(float f) {
  union { float f; u32 u; } v; v.f = f;
  u32 r = v.u + 0x7FFFu + ((v.u >> 16) & 1u);   // round-to-nearest-even
  return (u16)(r >> 16);
}
__device__ __forceinline__ u32 f2key(float f) {  // monotonic f32 -> u32
  union { float f; u32 u; } v; v.f = f;
  return (v.u & 0x80000000u) ? ~v.u : (v.u | 0x80000000u);
}

// ---------------- GEMM: C[M,N] = A[M,K] @ B[N,K]^T (both bf16 row-major) ----
// MODE 0: bf16 out, relu          (gemm1, static first-4096 mask)
// MODE 1: bf16 out, relu * mask   (gemm1, dynamic mask)
// MODE 2: f32 out, overwrite      (gemm2, first chunk)
// MODE 3: f32 out, accumulate     (gemm2, later chunks)
#define BM 128
#define BN 128
#define BK 64

template<int MODE>
__global__ __launch_bounds__(256, 2)
void gemm_bt(const u16* __restrict__ A, int lda,
             const u16* __restrict__ B, int ldb,
             void* __restrict__ Cv, int ldc,
             const float* __restrict__ mask, int mask_col0,
             int K, const int* __restrict__ gate)
{
  if (gate[0]) return;
  __shared__ alignas(16) u16 As[BM * BK];
  __shared__ alignas(16) u16 Bs[BN * BK];

  const int t = threadIdx.x;
  const int lane = t & 63;
  const int wave = t >> 6;
  const int wm = wave >> 1;
  const int wn = wave & 1;

  // XCD-aware swizzle (all our grids have nwg % 8 == 0)
  u32 nwg = gridDim.x * gridDim.y;
  u32 lin = blockIdx.y * gridDim.x + blockIdx.x;
  u32 swz = (lin & 7u) * (nwg >> 3) + (lin >> 3);
  int bx = swz % gridDim.x;
  int by = swz / gridDim.x;
  const int bm0 = by * BM;
  const int bn0 = bx * BN;

  f32x4 acc[4][4];
#pragma unroll
  for (int i = 0; i < 4; ++i)
#pragma unroll
    for (int j = 0; j < 4; ++j) acc[i][j] = (f32x4){0.f, 0.f, 0.f, 0.f};

  const int srow = t >> 3;  // staging row within a 32-row slab
  const int sblk = t & 7;   // 16B block within a 64-elem row

  const u16* Abase = A + (size_t)bm0 * lda;
  const u16* Bbase = B + (size_t)bn0 * ldb;

  for (int k0 = 0; k0 < K; k0 += BK) {
    // global -> LDS, linear LDS dest, inverse-XOR-swizzled global source
#pragma unroll
    for (int i = 0; i < 4; ++i) {
      int row = i * 32 + srow;
      int jsrc = sblk ^ (row & 7);
      const u16* ga = Abase + (size_t)row * lda + (k0 + jsrc * 8);
      const u16* gb = Bbase + (size_t)row * ldb + (k0 + jsrc * 8);
      __builtin_amdgcn_global_load_lds((GVoid*)ga, (LVoid*)(As + i * 2048 + wave * 512), 16, 0, 0);
      __builtin_amdgcn_global_load_lds((GVoid*)gb, (LVoid*)(Bs + i * 2048 + wave * 512), 16, 0, 0);
    }
    asm volatile("s_waitcnt vmcnt(0)" ::: "memory");
    __syncthreads();

#pragma unroll
    for (int ks = 0; ks < 2; ++ks) {
      bf16x8 av[4], bv[4];
#pragma unroll
      for (int i = 0; i < 4; ++i) {
        int arow = wm * 64 + i * 16 + (lane & 15);
        int kb = ks * 4 + (lane >> 4);
        av[i] = *(const bf16x8*)(As + arow * BK + ((kb ^ (arow & 7)) * 8));
        int brow = wn * 64 + i * 16 + (lane & 15);
        bv[i] = *(const bf16x8*)(Bs + brow * BK + ((kb ^ (brow & 7)) * 8));
      }
#pragma unroll
      for (int i = 0; i < 4; ++i)
#pragma unroll
        for (int j = 0; j < 4; ++j)
          acc[i][j] = __builtin_amdgcn_mfma_f32_16x16x32_bf16(av[i], bv[j], acc[i][j], 0, 0, 0);
    }
    __syncthreads();
  }

  // epilogue: C/D layout col=lane&15, row=(lane>>4)*4+r
#pragma unroll
  for (int i = 0; i < 4; ++i) {
    int row = bm0 + wm * 64 + i * 16 + ((lane >> 4) << 2);
#pragma unroll
    for (int j = 0; j < 4; ++j) {
      int col = bn0 + wn * 64 + j * 16 + (lane & 15);
      if (MODE <= 1) {
        float mval = 1.f;
        if (MODE == 1) mval = mask[(row >> 10) * FULL + mask_col0 + col];
        u16* C = (u16*)Cv;
#pragma unroll
        for (int r = 0; r < 4; ++r) {
          float v = fmaxf(acc[i][j][r] * mval, 0.f);
          C[(size_t)(row + r) * ldc + col] = f2b(v);
        }
      } else {
        float* C = (float*)Cv;
#pragma unroll
        for (int r = 0; r < 4; ++r) {
          size_t idx = (size_t)(row + r) * ldc + col;
          float v = acc[i][j][r];
          if (MODE == 3) v += C[idx];
          C[idx] = v;
        }
      }
    }
  }
}

// ---------------- small kernels ----------------
__global__ void init_state(float* active, float* history, int* flags, int* counts) {
  int i = blockIdx.x * blockDim.x + threadIdx.x;
  if (i < 4) flags[i] = 0;
  if (i < NB) counts[i] = 0;
  if (i < NB * FULL) {
    float v = ((i % FULL) < ITERSZ) ? 1.f : 0.f;
    active[i] = v;
    history[i] = v;
  }
}

__global__ void conv_f32_bf16(const float* __restrict__ src, u16* __restrict__ dst,
                              int n4, const int* __restrict__ gate) {
  if (gate[0]) return;
  int i = blockIdx.x * blockDim.x + threadIdx.x;
  int stride = gridDim.x * blockDim.x;
  for (; i < n4; i += stride) {
    float4 v = ((const float4*)src)[i];
    ushort4 o;
    o.x = f2b(v.x); o.y = f2b(v.y); o.z = f2b(v.z); o.w = f2b(v.w);
    ((ushort4*)dst)[i] = o;
  }
}

__global__ void pool_mean(const float* __restrict__ xn, float* __restrict__ pooled,
                          const int* __restrict__ gate) {
  if (gate[0]) return;
  int b = blockIdx.y;
  int c = blockIdx.x * blockDim.x + threadIdx.x;
  const float* p = xn + (size_t)b * (TT * NE) + c;
  float s = 0.f;
  for (int t2 = 0; t2 < TT; ++t2) s += p[(size_t)t2 * NE];
  pooled[b * NE + c] = s * (1.f / 1024.f);
}

__global__ void ctrl1(const float* __restrict__ pooled, const float* __restrict__ Wc1,
                      float* __restrict__ tmp, const int* __restrict__ gate) {
  if (gate[0]) return;
  int b = blockIdx.x;
  int d = threadIdx.x;  // 256
  const float* w = Wc1 + (size_t)d * NE;
  const float* p = pooled + b * NE;
  float s = 0.f;
  for (int c = 0; c < NE; ++c) s += p[c] * w[c];
  tmp[b * 256 + d] = fmaxf(s, 0.f);
}

__global__ void ctrl2(const float* __restrict__ tmp, const float* __restrict__ Wc2,
                      float* __restrict__ ck, const int* __restrict__ gate) {
  if (gate[0]) return;
  int b = blockIdx.y;
  int f = blockIdx.x * blockDim.x + threadIdx.x;
  const float* w = Wc2 + (size_t)f * 256;
  const float* p = tmp + b * 256;
  float s = 0.f;
  for (int d = 0; d < 256; ++d) s += p[d] * w[d];
  ck[b * FULL + f] = s;
}

// per-batch exact top-4096 via 4-pass radix select on monotonic keys
__global__ void topk_update(const float* __restrict__ ck, float* __restrict__ active,
                            float* __restrict__ history, int* __restrict__ counts,
                            const int* __restrict__ gate) {
  if (gate[0]) return;
  int b = blockIdx.x;
  const float* row = ck + (size_t)b * FULL;
  __shared__ int hist[256];
  __shared__ int s_bin, s_cum, s_eq, s_new;
  u32 prefix = 0;
  int k = ITERSZ;
  for (int pass = 3; pass >= 0; --pass) {
    hist[threadIdx.x] = 0;
    __syncthreads();
    u32 mhi = (pass == 3) ? 0u : (0xFFFFFFFFu << ((pass + 1) * 8));
    for (int f = threadIdx.x; f < FULL; f += 256) {
      u32 key = f2key(row[f]);
      if ((key & mhi) == (prefix & mhi))
        atomicAdd(&hist[(key >> (pass * 8)) & 255], 1);
    }
    __syncthreads();
    if (threadIdx.x == 0) {
      int cum = 0, bin = 255;
      for (; bin > 0; --bin) {
        if (cum + hist[bin] >= k) break;
        cum += hist[bin];
      }
      s_bin = bin; s_cum = cum;
    }
    __syncthreads();
    k -= s_cum;
    prefix |= ((u32)s_bin) << (pass * 8);
    __syncthreads();
  }
  if (threadIdx.x == 0) { s_eq = 0; s_new = 0; }
  __syncthreads();
  int newcnt = 0;
  for (int f = threadIdx.x; f < FULL; f += 256) {
    u32 key = f2key(row[f]);
    float m = 0.f;
    if (key > prefix) m = 1.f;
    else if (key == prefix && atomicAdd(&s_eq, 1) < k) m = 1.f;
    float h = history[b * FULL + f];
    float comb = fminf(h + m, 1.f);
    if (comb > h) newcnt++;
    active[b * FULL + f] = m;
    history[b * FULL + f] = comb;
  }
  atomicAdd(&s_new, newcnt);
  __syncthreads();
  if (threadIdx.x == 0) counts[b] = s_new;
}

__global__ void novelty_flag(const int* __restrict__ counts, int* __restrict__ flags, int it) {
  if (threadIdx.x == 0 && blockIdx.x == 0) {
    if (flags[it]) { flags[it + 1] = 1; return; }
    int s = 0;
    for (int b = 0; b < NB; ++b) s += counts[b];
    float nov = (float)s / (float)(NB * ITERSZ);
    flags[it + 1] = (nov < 0.7f) ? 1 : 0;
  }
}

extern "C" void kernel_launch(void* const* d_in, const int* in_sizes, int n_in,
                              void* d_out, int out_size, void* d_ws, size_t ws_size,
                              hipStream_t stream) {
  (void)in_sizes; (void)n_in; (void)out_size; (void)ws_size;
  const float* x   = (const float*)d_in[0];
  const float* Wm  = (const float*)d_in[1];
  const float* Wp  = (const float*)d_in[2];
  const float* Wc1 = (const float*)d_in[3];
  const float* Wc2 = (const float*)d_in[4];
  float* out = (float*)d_out;

  char* ws = (char*)d_ws;
  size_t off = 0;
  auto alloc = [&](size_t bytes) -> void* {
    void* p = ws + off;
    off += (bytes + 255) & ~(size_t)255;
    return p;
  };
  u16* Wm_bf = (u16*)alloc((size_t)FULL * NE * 2);
  u16* Wp_bf = (u16*)alloc((size_t)NE * FULL * 2);
  u16* x_bf  = (u16*)alloc((size_t)MROWS * NE * 2);
  u16* h_bf  = (u16*)alloc((size_t)MROWS * ITERSZ * 2);   // one 4096-col chunk
  float* active  = (float*)alloc((size_t)NB * FULL * 4);
  float* history = (float*)alloc((size_t)NB * FULL * 4);
  float* pooled  = (float*)alloc(NB * NE * 4);
  float* tmpc    = (float*)alloc(NB * 256 * 4);
  float* ck      = (float*)alloc((size_t)NB * FULL * 4);
  int* counts    = (int*)alloc(NB * 4);
  int* flags     = (int*)alloc(4 * 4);

  init_state<<<dim3((NB * FULL + 255) / 256), dim3(256), 0, stream>>>(active, history, flags, counts);
  conv_f32_bf16<<<dim3(1024), dim3(256), 0, stream>>>(Wm, Wm_bf, FULL * NE / 4, flags);
  conv_f32_bf16<<<dim3(1024), dim3(256), 0, stream>>>(Wp, Wp_bf, NE * FULL / 4, flags);
  conv_f32_bf16<<<dim3(1024), dim3(256), 0, stream>>>(x, x_bf, MROWS * NE / 4, flags);

  for (int it = 0; it < 3; ++it) {
    const int* gate = flags + it;
    const int nch = (it == 0) ? 1 : 3;   // step 0: static mask = first 4096 cols only
    for (int j = 0; j < nch; ++j) {
      if (it == 0) {
        gemm_bt<0><<<dim3(ITERSZ / BN, MROWS / BM), dim3(256), 0, stream>>>(
            x_bf, NE, Wm_bf, NE, h_bf, ITERSZ, nullptr, 0, NE, gate);
      } else {
        gemm_bt<1><<<dim3(ITERSZ / BN, MROWS / BM), dim3(256), 0, stream>>>(
            x_bf, NE, Wm_bf + (size_t)j * ITERSZ * NE, NE, h_bf, ITERSZ,
            active, j * ITERSZ, NE, gate);
      }
      if (j == 0) {
        gemm_bt<2><<<dim3(NE / BN, MROWS / BM), dim3(256), 0, stream>>>(
            h_bf, ITERSZ, Wp_bf + (size_t)j * ITERSZ, FULL, out, NE, nullptr, 0, ITERSZ, gate);
      } else {
        gemm_bt<3><<<dim3(NE / BN, MROWS / BM), dim3(256), 0, stream>>>(
            h_bf, ITERSZ, Wp_bf + (size_t)j * ITERSZ, FULL, out, NE, nullptr, 0, ITERSZ, gate);
      }
    }
    if (it < 2) {
      pool_mean<<<dim3(NE / 256, NB), dim3(256), 0, stream>>>(out, pooled, gate);
      ctrl1<<<dim3(NB), dim3(256), 0, stream>>>(pooled, Wc1, tmpc, gate);
      ctrl2<<<dim3(FULL / 256, NB), dim3(256), 0, stream>>>(tmpc, Wc2, ck, gate);
      topk_update<<<dim3(NB), dim3(256), 0, stream>>>(ck, active, history, counts, gate);
      novelty_flag<<<dim3(1), dim3(64), 0, stream>>>(counts, flags, it);
      // next-iteration input (skipped if done)
      conv_f32_bf16<<<dim3(1024), dim3(256), 0, stream>>>(out, x_bf, MROWS * NE / 4, flags + it + 1);
    }
  }
}

// Round 2
// 350.070 us; speedup vs baseline: 1.1943x; 1.1943x over previous
//
#include <hip/hip_runtime.h>

typedef unsigned short u16;
typedef unsigned int u32;

#define FULL 12288
#define NE 1024
#define ITERSZ 4096
#define NB 8
#define TT 1024
#define MROWS 8192

typedef __bf16 bf16x8 __attribute__((ext_vector_type(8)));
typedef float f32x4 __attribute__((ext_vector_type(4)));
typedef const __attribute__((address_space(1))) void GVoid;
typedef __attribute__((address_space(3))) void LVoid;

__device__ __forceinline__ u16 f2b(float f) {
  union { float f; u32 u; } v; v.f = f;
  u32 r = v.u + 0x7FFFu + ((v.u >> 16) & 1u);   // round-to-nearest-even
  return (u16)(r >> 16);
}
__device__ __forceinline__ u32 f2key(float f) {  // monotonic f32 -> u32
  union { float f; u32 u; } v; v.f = f;
  return (v.u & 0x80000000u) ? ~v.u : (v.u | 0x80000000u);
}

// ---------------- GEMM: C[M,N] = A[M,K] @ B[N,K]^T (both bf16 row-major) ----
// MODE 0: bf16 out, relu          (gemm1, static first-4096 mask)
// MODE 1: bf16 out, relu * mask   (gemm1, dynamic mask)
// MODE 2: f32 out, overwrite      (gemm2, first chunk)
// MODE 3: f32 out, accumulate     (gemm2, later chunks)
#define BM 128
#define BN 128
#define BK 64

template<int MODE>
__global__ __launch_bounds__(256, 2)
void gemm_bt(const u16* __restrict__ A, int lda,
             const u16* __restrict__ B, int ldb,
             void* __restrict__ Cv, int ldc,
             const float* __restrict__ mask, int mask_col0,
             int K, const int* __restrict__ gate)
{
  if (gate[0]) return;
  __shared__ alignas(16) u16 As[BM * BK];
  __shared__ alignas(16) u16 Bs[BN * BK];

  const int t = threadIdx.x;
  const int lane = t & 63;
  const int wave = t >> 6;
  const int wm = wave >> 1;
  const int wn = wave & 1;

  // XCD-aware swizzle (all our grids have nwg % 8 == 0)
  u32 nwg = gridDim.x * gridDim.y;
  u32 lin = blockIdx.y * gridDim.x + blockIdx.x;
  u32 swz = (lin & 7u) * (nwg >> 3) + (lin >> 3);
  int bx = swz % gridDim.x;
  int by = swz / gridDim.x;
  const int bm0 = by * BM;
  const int bn0 = bx * BN;

  f32x4 acc[4][4];
#pragma unroll
  for (int i = 0; i < 4; ++i)
#pragma unroll
    for (int j = 0; j < 4; ++j) acc[i][j] = (f32x4){0.f, 0.f, 0.f, 0.f};

  const int srow = t >> 3;  // staging row within a 32-row slab
  const int sblk = t & 7;   // 16B block within a 64-elem row

  const u16* Abase = A + (size_t)bm0 * lda;
  const u16* Bbase = B + (size_t)bn0 * ldb;

  for (int k0 = 0; k0 < K; k0 += BK) {
    // global -> LDS, linear LDS dest, inverse-XOR-swizzled global source
#pragma unroll
    for (int i = 0; i < 4; ++i) {
      int row = i * 32 + srow;
      int jsrc = sblk ^ (row & 7);
      const u16* ga = Abase + (size_t)row * lda + (k0 + jsrc * 8);
      const u16* gb = Bbase + (size_t)row * ldb + (k0 + jsrc * 8);
      __builtin_amdgcn_global_load_lds((GVoid*)ga, (LVoid*)(As + i * 2048 + wave * 512), 16, 0, 0);
      __builtin_amdgcn_global_load_lds((GVoid*)gb, (LVoid*)(Bs + i * 2048 + wave * 512), 16, 0, 0);
    }
    asm volatile("s_waitcnt vmcnt(0)" ::: "memory");
    __syncthreads();

#pragma unroll
    for (int ks = 0; ks < 2; ++ks) {
      bf16x8 av[4], bv[4];
#pragma unroll
      for (int i = 0; i < 4; ++i) {
        int arow = wm * 64 + i * 16 + (lane & 15);
        int kb = ks * 4 + (lane >> 4);
        av[i] = *(const bf16x8*)(As + arow * BK + ((kb ^ (arow & 7)) * 8));
        int brow = wn * 64 + i * 16 + (lane & 15);
        bv[i] = *(const bf16x8*)(Bs + brow * BK + ((kb ^ (brow & 7)) * 8));
      }
#pragma unroll
      for (int i = 0; i < 4; ++i)
#pragma unroll
        for (int j = 0; j < 4; ++j)
          acc[i][j] = __builtin_amdgcn_mfma_f32_16x16x32_bf16(av[i], bv[j], acc[i][j], 0, 0, 0);
    }
    __syncthreads();
  }

  // epilogue: C/D layout col=lane&15, row=(lane>>4)*4+r
#pragma unroll
  for (int i = 0; i < 4; ++i) {
    int row = bm0 + wm * 64 + i * 16 + ((lane >> 4) << 2);
#pragma unroll
    for (int j = 0; j < 4; ++j) {
      int col = bn0 + wn * 64 + j * 16 + (lane & 15);
      if (MODE <= 1) {
        float mval = 1.f;
        if (MODE == 1) mval = mask[(row >> 10) * FULL + mask_col0 + col];
        u16* C = (u16*)Cv;
#pragma unroll
        for (int r = 0; r < 4; ++r) {
          float v = fmaxf(acc[i][j][r] * mval, 0.f);
          C[(size_t)(row + r) * ldc + col] = f2b(v);
        }
      } else {
        float* C = (float*)Cv;
#pragma unroll
        for (int r = 0; r < 4; ++r) {
          size_t idx = (size_t)(row + r) * ldc + col;
          float v = acc[i][j][r];
          if (MODE == 3) v += C[idx];
          C[idx] = v;
        }
      }
    }
  }
}

// ---------------- small kernels ----------------
__global__ void init_state(float* active, float* history, int* flags, int* counts) {
  int i = blockIdx.x * blockDim.x + threadIdx.x;
  if (i < 4) flags[i] = 0;
  if (i < NB) counts[i] = 0;
  if (i < NB * FULL) {
    float v = ((i % FULL) < ITERSZ) ? 1.f : 0.f;
    active[i] = v;
    history[i] = v;
  }
}

__global__ void conv_f32_bf16(const float* __restrict__ src, u16* __restrict__ dst,
                              int n4, const int* __restrict__ gate) {
  if (gate[0]) return;
  int i = blockIdx.x * blockDim.x + threadIdx.x;
  int stride = gridDim.x * blockDim.x;
  for (; i < n4; i += stride) {
    float4 v = ((const float4*)src)[i];
    ushort4 o;
    o.x = f2b(v.x); o.y = f2b(v.y); o.z = f2b(v.z); o.w = f2b(v.w);
    ((ushort4*)dst)[i] = o;
  }
}

__global__ void pool_mean(const float* __restrict__ xn, float* __restrict__ pooled,
                          const int* __restrict__ gate) {
  if (gate[0]) return;
  int b = blockIdx.y;
  int c = blockIdx.x * blockDim.x + threadIdx.x;
  const float* p = xn + (size_t)b * (TT * NE) + c;
  float s = 0.f;
  for (int t2 = 0; t2 < TT; ++t2) s += p[(size_t)t2 * NE];
  pooled[b * NE + c] = s * (1.f / 1024.f);
}

__global__ void ctrl1(const float* __restrict__ pooled, const float* __restrict__ Wc1,
                      float* __restrict__ tmp, const int* __restrict__ gate) {
  if (gate[0]) return;
  int b = blockIdx.x;
  int d = threadIdx.x;  // 256
  const float* w = Wc1 + (size_t)d * NE;
  const float* p = pooled + b * NE;
  float s = 0.f;
  for (int c = 0; c < NE; ++c) s += p[c] * w[c];
  tmp[b * 256 + d] = fmaxf(s, 0.f);
}

// one block per 256-col slab of ck; all 8 batches per block (Wc2 read once)
__global__ void ctrl2(const float* __restrict__ tmp, const float* __restrict__ Wc2,
                      float* __restrict__ ck, const int* __restrict__ gate) {
  if (gate[0]) return;
  __shared__ float st[NB * 256];
  int t = threadIdx.x;  // 256
  for (int i = t; i < NB * 256; i += 256) st[i] = tmp[i];
  __syncthreads();
  int f = blockIdx.x * 256 + t;
  const float* w = Wc2 + (size_t)f * 256;
  float s[NB];
#pragma unroll
  for (int b = 0; b < NB; ++b) s[b] = 0.f;
  for (int d = 0; d < 256; ++d) {
    float wv = w[d];
#pragma unroll
    for (int b = 0; b < NB; ++b) s[b] += st[b * 256 + d] * wv;
  }
#pragma unroll
  for (int b = 0; b < NB; ++b) ck[(size_t)b * FULL + f] = s[b];
}

// per-batch exact top-4096 via 4-pass radix select; keys cached in LDS,
// parallel suffix-scan for bin selection (was thread-0 serial: 90us -> ~5us)
__global__ __launch_bounds__(1024)
void topk_update(const float* __restrict__ ck, float* __restrict__ active,
                 float* __restrict__ history, int* __restrict__ counts,
                 const int* __restrict__ gate) {
  if (gate[0]) return;
  int b = blockIdx.x;
  int t = threadIdx.x;  // 1024
  const float* row = ck + (size_t)b * FULL;
  __shared__ u32 skeys[FULL];
  __shared__ int hist[256];
  __shared__ int scan[256];
  __shared__ int s_bin, s_cum, s_eq, s_new;

  for (int f = t; f < FULL; f += 1024) skeys[f] = f2key(row[f]);
  __syncthreads();

  u32 prefix = 0;
  int k = ITERSZ;
  for (int pass = 3; pass >= 0; --pass) {
    if (t < 256) hist[t] = 0;
    __syncthreads();
    u32 mhi = (pass == 3) ? 0u : (0xFFFFFFFFu << ((pass + 1) * 8));
    for (int f = t; f < FULL; f += 1024) {
      u32 key = skeys[f];
      if ((key & mhi) == (prefix & mhi))
        atomicAdd(&hist[(key >> (pass * 8)) & 255], 1);
    }
    __syncthreads();
    // inclusive suffix-sum over 256 bins (scan[t] = sum_{j>=t} hist[j])
    if (t < 256) scan[t] = hist[t];
    __syncthreads();
    for (int d = 1; d < 256; d <<= 1) {
      int v = 0;
      if (t < 256) v = scan[t] + ((t + d < 256) ? scan[t + d] : 0);
      __syncthreads();
      if (t < 256) scan[t] = v;
      __syncthreads();
    }
    // chosen bin = max t with suffix >= k (scan non-increasing -> unique)
    if (t < 256) {
      if (scan[t] >= k && (t == 255 || scan[t + 1] < k)) {
        s_bin = t;
        s_cum = (t == 255) ? 0 : scan[t + 1];
      }
    }
    __syncthreads();
    k -= s_cum;
    prefix |= ((u32)s_bin) << (pass * 8);
    __syncthreads();
  }
  if (t == 0) { s_eq = 0; s_new = 0; }
  __syncthreads();

  int newcnt = 0;
  for (int f = t; f < FULL; f += 1024) {
    u32 key = skeys[f];
    float m = 0.f;
    if (key > prefix) m = 1.f;
    else if (key == prefix && atomicAdd(&s_eq, 1) < k) m = 1.f;
    float h = history[b * FULL + f];
    float comb = fminf(h + m, 1.f);
    if (comb > h) newcnt++;
    active[b * FULL + f] = m;
    history[b * FULL + f] = comb;
  }
#pragma unroll
  for (int o = 32; o > 0; o >>= 1) newcnt += __shfl_down(newcnt, o, 64);
  if ((t & 63) == 0) atomicAdd(&s_new, newcnt);
  __syncthreads();
  if (t == 0) counts[b] = s_new;
}

__global__ void novelty_flag(const int* __restrict__ counts, int* __restrict__ flags, int it) {
  if (threadIdx.x == 0 && blockIdx.x == 0) {
    if (flags[it]) { flags[it + 1] = 1; return; }
    int s = 0;
    for (int b = 0; b < NB; ++b) s += counts[b];
    float nov = (float)s / (float)(NB * ITERSZ);
    flags[it + 1] = (nov < 0.7f) ? 1 : 0;
  }
}

extern "C" void kernel_launch(void* const* d_in, const int* in_sizes, int n_in,
                              void* d_out, int out_size, void* d_ws, size_t ws_size,
                              hipStream_t stream) {
  (void)in_sizes; (void)n_in; (void)out_size; (void)ws_size;
  const float* x   = (const float*)d_in[0];
  const float* Wm  = (const float*)d_in[1];
  const float* Wp  = (const float*)d_in[2];
  const float* Wc1 = (const float*)d_in[3];
  const float* Wc2 = (const float*)d_in[4];
  float* out = (float*)d_out;

  char* ws = (char*)d_ws;
  size_t off = 0;
  auto alloc = [&](size_t bytes) -> void* {
    void* p = ws + off;
    off += (bytes + 255) & ~(size_t)255;
    return p;
  };
  u16* Wm_bf = (u16*)alloc((size_t)FULL * NE * 2);
  u16* Wp_bf = (u16*)alloc((size_t)NE * FULL * 2);
  u16* x_bf  = (u16*)alloc((size_t)MROWS * NE * 2);
  u16* h_bf  = (u16*)alloc((size_t)MROWS * ITERSZ * 2);   // one 4096-col chunk
  float* active  = (float*)alloc((size_t)NB * FULL * 4);
  float* history = (float*)alloc((size_t)NB * FULL * 4);
  float* pooled  = (float*)alloc(NB * NE * 4);
  float* tmpc    = (float*)alloc(NB * 256 * 4);
  float* ck      = (float*)alloc((size_t)NB * FULL * 4);
  int* counts    = (int*)alloc(NB * 4);
  int* flags     = (int*)alloc(4 * 4);

  init_state<<<dim3((NB * FULL + 255) / 256), dim3(256), 0, stream>>>(active, history, flags, counts);
  conv_f32_bf16<<<dim3(1024), dim3(256), 0, stream>>>(Wm, Wm_bf, FULL * NE / 4, flags);
  conv_f32_bf16<<<dim3(1024), dim3(256), 0, stream>>>(Wp, Wp_bf, NE * FULL / 4, flags);
  conv_f32_bf16<<<dim3(1024), dim3(256), 0, stream>>>(x, x_bf, MROWS * NE / 4, flags);

  for (int it = 0; it < 3; ++it) {
    const int* gate = flags + it;
    const int nch = (it == 0) ? 1 : 3;   // step 0: static mask = first 4096 cols only
    for (int j = 0; j < nch; ++j) {
      if (it == 0) {
        gemm_bt<0><<<dim3(ITERSZ / BN, MROWS / BM), dim3(256), 0, stream>>>(
            x_bf, NE, Wm_bf, NE, h_bf, ITERSZ, nullptr, 0, NE, gate);
      } else {
        gemm_bt<1><<<dim3(ITERSZ / BN, MROWS / BM), dim3(256), 0, stream>>>(
            x_bf, NE, Wm_bf + (size_t)j * ITERSZ * NE, NE, h_bf, ITERSZ,
            active, j * ITERSZ, NE, gate);
      }
      if (j == 0) {
        gemm_bt<2><<<dim3(NE / BN, MROWS / BM), dim3(256), 0, stream>>>(
            h_bf, ITERSZ, Wp_bf + (size_t)j * ITERSZ, FULL, out, NE, nullptr, 0, ITERSZ, gate);
      } else {
        gemm_bt<3><<<dim3(NE / BN, MROWS / BM), dim3(256), 0, stream>>>(
            h_bf, ITERSZ, Wp_bf + (size_t)j * ITERSZ, FULL, out, NE, nullptr, 0, ITERSZ, gate);
      }
    }
    if (it < 2) {
      pool_mean<<<dim3(NE / 256, NB), dim3(256), 0, stream>>>(out, pooled, gate);
      ctrl1<<<dim3(NB), dim3(256), 0, stream>>>(pooled, Wc1, tmpc, gate);
      ctrl2<<<dim3(FULL / 256), dim3(256), 0, stream>>>(tmpc, Wc2, ck, gate);
      topk_update<<<dim3(NB), dim3(1024), 0, stream>>>(ck, active, history, counts, gate);
      novelty_flag<<<dim3(1), dim3(64), 0, stream>>>(counts, flags, it);
      // next-iteration input (skipped if done)
      conv_f32_bf16<<<dim3(1024), dim3(256), 0, stream>>>(out, x_bf, MROWS * NE / 4, flags + it + 1);
    }
  }
}

// Round 3
// 270.330 us; speedup vs baseline: 1.5466x; 1.2950x over previous
//
#include <hip/hip_runtime.h>

typedef unsigned short u16;
typedef unsigned int u32;

#define FULL 12288
#define NE 1024
#define ITERSZ 4096
#define NB 8
#define TT 1024
#define MROWS 8192

typedef __bf16 bf16x8 __attribute__((ext_vector_type(8)));
typedef float f32x4 __attribute__((ext_vector_type(4)));
typedef const __attribute__((address_space(1))) void GVoid;
typedef __attribute__((address_space(3))) void LVoid;

__device__ __forceinline__ u16 f2b(float f) {
  union { float f; u32 u; } v; v.f = f;
  u32 r = v.u + 0x7FFFu + ((v.u >> 16) & 1u);   // round-to-nearest-even
  return (u16)(r >> 16);
}
__device__ __forceinline__ u32 f2key(float f) {  // monotonic f32 -> u32
  union { float f; u32 u; } v; v.f = f;
  return (v.u & 0x80000000u) ? ~v.u : (v.u | 0x80000000u);
}
__device__ __forceinline__ void cp4(const float* s, u16* d, size_t i_s, size_t i_d) {
  float4 v = ((const float4*)s)[i_s];
  ushort4 o;
  o.x = f2b(v.x); o.y = f2b(v.y); o.z = f2b(v.z); o.w = f2b(v.w);
  ((ushort4*)d)[i_d] = o;
}

// ---------------- GEMM: C[M,N] = A[M,K] @ B[N,K]^T (both bf16 row-major) ----
// MODE 0: bf16 out, relu          (gemm1, static first-4096 mask)
// MODE 1: bf16 out, relu * mask   (gemm1, dynamic mask)
// MODE 2: f32 out, overwrite      (gemm2, first chunk)  [+ optional fused pool]
// MODE 3: f32 out, accumulate     (gemm2, later chunks) [+ optional fused pool]
#define BM 128
#define BN 128
#define BK 64

template<int MODE>
__global__ __launch_bounds__(256, 2)
void gemm_bt(const u16* __restrict__ A, int lda,
             const u16* __restrict__ B, int ldb,
             void* __restrict__ Cv, int ldc,
             const float* __restrict__ mask, int mask_col0,
             int K, const int* __restrict__ gate,
             float* __restrict__ pooled)
{
  if (gate[0]) return;
  __shared__ alignas(16) u16 As[BM * BK];
  __shared__ alignas(16) u16 Bs[BN * BK];

  const int t = threadIdx.x;
  const int lane = t & 63;
  const int wave = t >> 6;
  const int wm = wave >> 1;
  const int wn = wave & 1;

  // XCD-aware swizzle (all our grids have nwg % 8 == 0)
  u32 nwg = gridDim.x * gridDim.y;
  u32 lin = blockIdx.y * gridDim.x + blockIdx.x;
  u32 swz = (lin & 7u) * (nwg >> 3) + (lin >> 3);
  int bx = swz % gridDim.x;
  int by = swz / gridDim.x;
  const int bm0 = by * BM;
  const int bn0 = bx * BN;

  f32x4 acc[4][4];
#pragma unroll
  for (int i = 0; i < 4; ++i)
#pragma unroll
    for (int j = 0; j < 4; ++j) acc[i][j] = (f32x4){0.f, 0.f, 0.f, 0.f};

  const int srow = t >> 3;  // staging row within a 32-row slab
  const int sblk = t & 7;   // 16B block within a 64-elem row

  const u16* Abase = A + (size_t)bm0 * lda;
  const u16* Bbase = B + (size_t)bn0 * ldb;

  for (int k0 = 0; k0 < K; k0 += BK) {
    // global -> LDS, linear LDS dest, inverse-XOR-swizzled global source
#pragma unroll
    for (int i = 0; i < 4; ++i) {
      int row = i * 32 + srow;
      int jsrc = sblk ^ (row & 7);
      const u16* ga = Abase + (size_t)row * lda + (k0 + jsrc * 8);
      const u16* gb = Bbase + (size_t)row * ldb + (k0 + jsrc * 8);
      __builtin_amdgcn_global_load_lds((GVoid*)ga, (LVoid*)(As + i * 2048 + wave * 512), 16, 0, 0);
      __builtin_amdgcn_global_load_lds((GVoid*)gb, (LVoid*)(Bs + i * 2048 + wave * 512), 16, 0, 0);
    }
    asm volatile("s_waitcnt vmcnt(0)" ::: "memory");
    __syncthreads();

#pragma unroll
    for (int ks = 0; ks < 2; ++ks) {
      bf16x8 av[4], bv[4];
#pragma unroll
      for (int i = 0; i < 4; ++i) {
        int arow = wm * 64 + i * 16 + (lane & 15);
        int kb = ks * 4 + (lane >> 4);
        av[i] = *(const bf16x8*)(As + arow * BK + ((kb ^ (arow & 7)) * 8));
        int brow = wn * 64 + i * 16 + (lane & 15);
        bv[i] = *(const bf16x8*)(Bs + brow * BK + ((kb ^ (brow & 7)) * 8));
      }
#pragma unroll
      for (int i = 0; i < 4; ++i)
#pragma unroll
        for (int j = 0; j < 4; ++j)
          acc[i][j] = __builtin_amdgcn_mfma_f32_16x16x32_bf16(av[i], bv[j], acc[i][j], 0, 0, 0);
    }
    __syncthreads();
  }

  // epilogue: C/D layout col=lane&15, row=(lane>>4)*4+r
#pragma unroll
  for (int i = 0; i < 4; ++i) {
    int row = bm0 + wm * 64 + i * 16 + ((lane >> 4) << 2);
#pragma unroll
    for (int j = 0; j < 4; ++j) {
      int col = bn0 + wn * 64 + j * 16 + (lane & 15);
      if (MODE <= 1) {
        float mval = 1.f;
        if (MODE == 1) mval = mask[(row >> 10) * FULL + mask_col0 + col];
        u16* C = (u16*)Cv;
#pragma unroll
        for (int r = 0; r < 4; ++r) {
          float v = fmaxf(acc[i][j][r] * mval, 0.f);
          C[(size_t)(row + r) * ldc + col] = f2b(v);
        }
      } else {
        float* C = (float*)Cv;
#pragma unroll
        for (int r = 0; r < 4; ++r) {
          size_t idx = (size_t)(row + r) * ldc + col;
          float v = acc[i][j][r];
          if (MODE == 3) v += C[idx];
          C[idx] = v;
        }
      }
    }
  }

  // fused column-sum for pooling (gemm2 only): pooled[b][c] += sum over block rows
  if (MODE >= 2) {
    if (pooled != nullptr) {
      int batch = bm0 >> 10;   // 1024 rows per batch, BM=128 divides it
#pragma unroll
      for (int j = 0; j < 4; ++j) {
        float cs = 0.f;
#pragma unroll
        for (int i = 0; i < 4; ++i)
#pragma unroll
          for (int r = 0; r < 4; ++r) cs += acc[i][j][r];
        cs += __shfl_xor(cs, 16, 64);
        cs += __shfl_xor(cs, 32, 64);
        if (lane < 16)
          atomicAdd(&pooled[batch * NE + bn0 + wn * 64 + j * 16 + lane], cs);
      }
    }
  }
}

// ---------------- small kernels ----------------
__global__ void init_state(float* active, float* history, int* flags,
                           int* nov_sum, int* done_ctr, float* pooled) {
  int i = blockIdx.x * blockDim.x + threadIdx.x;
  if (i < 4) flags[i] = 0;
  if (i < 3) { nov_sum[i] = 0; done_ctr[i] = 0; }
  if (i < NB * NE) pooled[i] = 0.f;
  if (i < NB * FULL) {
    float v = ((i % FULL) < ITERSZ) ? 1.f : 0.f;
    active[i] = v;
    history[i] = v;
  }
}

// ungated: convert exactly what step 0 needs (Wm rows [0,4096), Wp cols [0,4096), x)
__global__ void conv_step0(const float* __restrict__ Wm, const float* __restrict__ Wp,
                           const float* __restrict__ x,
                           u16* __restrict__ Wm_bf, u16* __restrict__ Wp_bf,
                           u16* __restrict__ x_bf) {
  const int N1 = (ITERSZ * NE) / 4;   // 1048576 f4 : Wm rows 0..4095 (linear)
  const int N2 = (NE * ITERSZ) / 4;   // 1048576 f4 : Wp cols 0..4095 (strided rows)
  const int N3 = (MROWS * NE) / 4;    // 2097152 f4 : x (linear)
  int i = blockIdx.x * blockDim.x + threadIdx.x;
  int stride = gridDim.x * blockDim.x;
  for (; i < N1 + N2 + N3; i += stride) {
    if (i < N1) {
      cp4(Wm, Wm_bf, i, i);
    } else if (i < N1 + N2) {
      int k = i - N1;
      int r = k >> 10, c4 = k & 1023;            // 4096 cols -> 1024 f4/row
      size_t idx = (size_t)r * (FULL / 4) + c4;  // keep full-stride layout
      cp4(Wp, Wp_bf, idx, idx);
    } else {
      int k = i - N1 - N2;
      cp4(x, x_bf, k, k);
    }
  }
}

// gated on flags[1]: remainder of Wm/Wp + next-step x <- out
__global__ void conv_rest(const float* __restrict__ Wm, const float* __restrict__ Wp,
                          const float* __restrict__ out,
                          u16* __restrict__ Wm_bf, u16* __restrict__ Wp_bf,
                          u16* __restrict__ x_bf, const int* __restrict__ gate) {
  if (gate[0]) return;
  const int N1 = ((FULL - ITERSZ) * NE) / 4;   // 2097152 f4 : Wm rows 4096..
  const int N2 = (NE * (FULL - ITERSZ)) / 4;   // 2097152 f4 : Wp cols 4096..
  const int N3 = (MROWS * NE) / 4;             // 2097152 f4 : x <- out
  const int base1 = (ITERSZ * NE) / 4;
  int i = blockIdx.x * blockDim.x + threadIdx.x;
  int stride = gridDim.x * blockDim.x;
  for (; i < N1 + N2 + N3; i += stride) {
    if (i < N1) {
      cp4(Wm, Wm_bf, base1 + i, base1 + i);
    } else if (i < N1 + N2) {
      int k = i - N1;
      int r = k >> 11, c4 = k & 2047;            // 8192 cols -> 2048 f4/row
      size_t idx = (size_t)r * (FULL / 4) + (ITERSZ / 4) + c4;
      cp4(Wp, Wp_bf, idx, idx);
    } else {
      int k = i - N1 - N2;
      cp4(out, x_bf, k, k);
    }
  }
}

// gated on flags[2]: x <- out for step 2
__global__ void conv_x2(const float* __restrict__ out, u16* __restrict__ x_bf,
                        const int* __restrict__ gate) {
  if (gate[0]) return;
  const int N = (MROWS * NE) / 4;
  int i = blockIdx.x * blockDim.x + threadIdx.x;
  int stride = gridDim.x * blockDim.x;
  for (; i < N; i += stride) cp4(out, x_bf, i, i);
}

__global__ void zero_pooled(float* pooled, const int* __restrict__ gate) {
  if (gate[0]) return;
  int i = blockIdx.x * blockDim.x + threadIdx.x;
  if (i < NB * NE / 4) ((float4*)pooled)[i] = (float4){0.f, 0.f, 0.f, 0.f};
}

// pooled holds SUM over T; fold the 1/1024 here
__global__ void ctrl1(const float* __restrict__ pooled, const float* __restrict__ Wc1,
                      float* __restrict__ tmp, const int* __restrict__ gate) {
  if (gate[0]) return;
  int b = blockIdx.x;
  int d = threadIdx.x;  // 256
  const float* w = Wc1 + (size_t)d * NE;
  const float* p = pooled + b * NE;
  float s = 0.f;
  for (int c = 0; c < NE; ++c) s += p[c] * w[c];
  tmp[b * 256 + d] = fmaxf(s * (1.f / 1024.f), 0.f);
}

// one block per 256-col slab of ck; all 8 batches per block (Wc2 read once)
__global__ void ctrl2(const float* __restrict__ tmp, const float* __restrict__ Wc2,
                      float* __restrict__ ck, const int* __restrict__ gate) {
  if (gate[0]) return;
  __shared__ float st[NB * 256];
  int t = threadIdx.x;  // 256
  for (int i = t; i < NB * 256; i += 256) st[i] = tmp[i];
  __syncthreads();
  int f = blockIdx.x * 256 + t;
  const float* w = Wc2 + (size_t)f * 256;
  float s[NB];
#pragma unroll
  for (int b = 0; b < NB; ++b) s[b] = 0.f;
  for (int d = 0; d < 256; ++d) {
    float wv = w[d];
#pragma unroll
    for (int b = 0; b < NB; ++b) s[b] += st[b * 256 + d] * wv;
  }
#pragma unroll
  for (int b = 0; b < NB; ++b) ck[(size_t)b * FULL + f] = s[b];
}

// per-batch exact top-4096 via 4-pass radix select; keys in LDS, parallel
// suffix-scan bin selection; novelty check fused (last-finisher sets flag)
__global__ __launch_bounds__(1024)
void topk_update(const float* __restrict__ ck, float* __restrict__ active,
                 float* __restrict__ history, int* __restrict__ flags,
                 int* __restrict__ nov_sum, int* __restrict__ done_ctr, int it) {
  if (flags[it]) {
    if (blockIdx.x == 0 && threadIdx.x == 0) flags[it + 1] = 1;  // propagate done
    return;
  }
  int b = blockIdx.x;
  int t = threadIdx.x;  // 1024
  const float* row = ck + (size_t)b * FULL;
  __shared__ u32 skeys[FULL];
  __shared__ int hist[256];
  __shared__ int scan[256];
  __shared__ int s_bin, s_cum, s_eq, s_new;

  for (int f = t; f < FULL; f += 1024) skeys[f] = f2key(row[f]);
  __syncthreads();

  u32 prefix = 0;
  int k = ITERSZ;
  for (int pass = 3; pass >= 0; --pass) {
    if (t < 256) hist[t] = 0;
    __syncthreads();
    u32 mhi = (pass == 3) ? 0u : (0xFFFFFFFFu << ((pass + 1) * 8));
    for (int f = t; f < FULL; f += 1024) {
      u32 key = skeys[f];
      if ((key & mhi) == (prefix & mhi))
        atomicAdd(&hist[(key >> (pass * 8)) & 255], 1);
    }
    __syncthreads();
    // inclusive suffix-sum over 256 bins (scan[t] = sum_{j>=t} hist[j])
    if (t < 256) scan[t] = hist[t];
    __syncthreads();
    for (int d = 1; d < 256; d <<= 1) {
      int v = 0;
      if (t < 256) v = scan[t] + ((t + d < 256) ? scan[t + d] : 0);
      __syncthreads();
      if (t < 256) scan[t] = v;
      __syncthreads();
    }
    // chosen bin = max t with suffix >= k (scan non-increasing -> unique)
    if (t < 256) {
      if (scan[t] >= k && (t == 255 || scan[t + 1] < k)) {
        s_bin = t;
        s_cum = (t == 255) ? 0 : scan[t + 1];
      }
    }
    __syncthreads();
    k -= s_cum;
    prefix |= ((u32)s_bin) << (pass * 8);
    __syncthreads();
  }
  if (t == 0) { s_eq = 0; s_new = 0; }
  __syncthreads();

  int newcnt = 0;
  for (int f = t; f < FULL; f += 1024) {
    u32 key = skeys[f];
    float m = 0.f;
    if (key > prefix) m = 1.f;
    else if (key == prefix && atomicAdd(&s_eq, 1) < k) m = 1.f;
    float h = history[b * FULL + f];
    float comb = fminf(h + m, 1.f);
    if (comb > h) newcnt++;
    active[b * FULL + f] = m;
    history[b * FULL + f] = comb;
  }
#pragma unroll
  for (int o = 32; o > 0; o >>= 1) newcnt += __shfl_down(newcnt, o, 64);
  if ((t & 63) == 0) atomicAdd(&s_new, newcnt);
  __syncthreads();

  if (t == 0) {
    atomicAdd(&nov_sum[it], s_new);
    __threadfence();
    int prev = atomicAdd(&done_ctr[it], 1);
    if (prev == NB - 1) {              // last block to finish computes the flag
      __threadfence();
      int s = atomicAdd(&nov_sum[it], 0);
      float nov = (float)s * (1.f / (NB * ITERSZ));
      flags[it + 1] = (nov < 0.7f) ? 1 : 0;
    }
  }
}

extern "C" void kernel_launch(void* const* d_in, const int* in_sizes, int n_in,
                              void* d_out, int out_size, void* d_ws, size_t ws_size,
                              hipStream_t stream) {
  (void)in_sizes; (void)n_in; (void)out_size; (void)ws_size;
  const float* x   = (const float*)d_in[0];
  const float* Wm  = (const float*)d_in[1];
  const float* Wp  = (const float*)d_in[2];
  const float* Wc1 = (const float*)d_in[3];
  const float* Wc2 = (const float*)d_in[4];
  float* out = (float*)d_out;

  char* ws = (char*)d_ws;
  size_t off = 0;
  auto alloc = [&](size_t bytes) -> void* {
    void* p = ws + off;
    off += (bytes + 255) & ~(size_t)255;
    return p;
  };
  u16* Wm_bf = (u16*)alloc((size_t)FULL * NE * 2);
  u16* Wp_bf = (u16*)alloc((size_t)NE * FULL * 2);
  u16* x_bf  = (u16*)alloc((size_t)MROWS * NE * 2);
  u16* h_bf  = (u16*)alloc((size_t)MROWS * ITERSZ * 2);   // one 4096-col chunk
  float* active  = (float*)alloc((size_t)NB * FULL * 4);
  float* history = (float*)alloc((size_t)NB * FULL * 4);
  float* pooled  = (float*)alloc(NB * NE * 4);
  float* tmpc    = (float*)alloc(NB * 256 * 4);
  float* ck      = (float*)alloc((size_t)NB * FULL * 4);
  int* nov_sum   = (int*)alloc(3 * 4);
  int* done_ctr  = (int*)alloc(3 * 4);
  int* flags     = (int*)alloc(4 * 4);

  init_state<<<dim3((NB * FULL + 255) / 256), dim3(256), 0, stream>>>(
      active, history, flags, nov_sum, done_ctr, pooled);
  conv_step0<<<dim3(2048), dim3(256), 0, stream>>>(Wm, Wp, x, Wm_bf, Wp_bf, x_bf);

  // ---- it = 0 (static first-4096 mask) ----
  gemm_bt<0><<<dim3(ITERSZ / BN, MROWS / BM), dim3(256), 0, stream>>>(
      x_bf, NE, Wm_bf, NE, h_bf, ITERSZ, nullptr, 0, NE, flags, nullptr);
  gemm_bt<2><<<dim3(NE / BN, MROWS / BM), dim3(256), 0, stream>>>(
      h_bf, ITERSZ, Wp_bf, FULL, out, NE, nullptr, 0, ITERSZ, flags, pooled);
  ctrl1<<<dim3(NB), dim3(256), 0, stream>>>(pooled, Wc1, tmpc, flags);
  ctrl2<<<dim3(FULL / 256), dim3(256), 0, stream>>>(tmpc, Wc2, ck, flags);
  topk_update<<<dim3(NB), dim3(1024), 0, stream>>>(ck, active, history, flags,
                                                   nov_sum, done_ctr, 0);

  // ---- it = 1 (gated on flags[1]) ----
  conv_rest<<<dim3(2048), dim3(256), 0, stream>>>(Wm, Wp, out, Wm_bf, Wp_bf, x_bf, flags + 1);
  zero_pooled<<<dim3(8), dim3(256), 0, stream>>>(pooled, flags + 1);
  for (int j = 0; j < 3; ++j) {
    gemm_bt<1><<<dim3(ITERSZ / BN, MROWS / BM), dim3(256), 0, stream>>>(
        x_bf, NE, Wm_bf + (size_t)j * ITERSZ * NE, NE, h_bf, ITERSZ,
        active, j * ITERSZ, NE, flags + 1, nullptr);
    if (j == 0)
      gemm_bt<2><<<dim3(NE / BN, MROWS / BM), dim3(256), 0, stream>>>(
          h_bf, ITERSZ, Wp_bf + (size_t)j * ITERSZ, FULL, out, NE, nullptr, 0,
          ITERSZ, flags + 1, pooled);
    else
      gemm_bt<3><<<dim3(NE / BN, MROWS / BM), dim3(256), 0, stream>>>(
          h_bf, ITERSZ, Wp_bf + (size_t)j * ITERSZ, FULL, out, NE, nullptr, 0,
          ITERSZ, flags + 1, pooled);
  }
  ctrl1<<<dim3(NB), dim3(256), 0, stream>>>(pooled, Wc1, tmpc, flags + 1);
  ctrl2<<<dim3(FULL / 256), dim3(256), 0, stream>>>(tmpc, Wc2, ck, flags + 1);
  topk_update<<<dim3(NB), dim3(1024), 0, stream>>>(ck, active, history, flags,
                                                   nov_sum, done_ctr, 1);

  // ---- it = 2 (gated on flags[2]; no control phase afterwards) ----
  conv_x2<<<dim3(2048), dim3(256), 0, stream>>>(out, x_bf, flags + 2);
  for (int j = 0; j < 3; ++j) {
    gemm_bt<1><<<dim3(ITERSZ / BN, MROWS / BM), dim3(256), 0, stream>>>(
        x_bf, NE, Wm_bf + (size_t)j * ITERSZ * NE, NE, h_bf, ITERSZ,
        active, j * ITERSZ, NE, flags + 2, nullptr);
    if (j == 0)
      gemm_bt<2><<<dim3(NE / BN, MROWS / BM), dim3(256), 0, stream>>>(
          h_bf, ITERSZ, Wp_bf + (size_t)j * ITERSZ, FULL, out, NE, nullptr, 0,
          ITERSZ, flags + 2, nullptr);
    else
      gemm_bt<3><<<dim3(NE / BN, MROWS / BM), dim3(256), 0, stream>>>(
          h_bf, ITERSZ, Wp_bf + (size_t)j * ITERSZ, FULL, out, NE, nullptr, 0,
          ITERSZ, flags + 2, nullptr);
  }
}